// Round 2
// 395.886 us; speedup vs baseline: 1.0745x; 1.0745x over previous
//
#include <hip/hip_runtime.h>
#include <hip/hip_bf16.h>
#include <hip/hip_fp16.h>

typedef __hip_bfloat16 bf16;
typedef __attribute__((ext_vector_type(8))) short short8;
typedef __attribute__((ext_vector_type(4))) float f32x4;

#define EPS 1e-5f
#define NSLOPE 0.01f

__device__ __forceinline__ float b2f(bf16 v) { return __bfloat162float(v); }

__device__ __forceinline__ float ld1(const void* p, size_t idx, int isbf) {
  if (isbf) return b2f(((const bf16*)p)[idx]);
  return ((const float*)p)[idx];
}
__device__ __forceinline__ void st1(void* p, size_t idx, int isbf, float v) {
  if (isbf) ((bf16*)p)[idx] = __float2bfloat16(v);
  else      ((float*)p)[idx] = v;
}
__device__ __forceinline__ short f2bs(float x) {
  bf16 t = __float2bfloat16(x);
  short s; __builtin_memcpy(&s, &t, 2); return s;
}
// pack 8 consecutive floats -> short8 of bf16
__device__ __forceinline__ short8 pack8f(const float* p) {
  float4 a = *(const float4*)p, b = *(const float4*)(p + 4);
  short8 r;
  r[0] = f2bs(a.x); r[1] = f2bs(a.y); r[2] = f2bs(a.z); r[3] = f2bs(a.w);
  r[4] = f2bs(b.x); r[5] = f2bs(b.y); r[6] = f2bs(b.z); r[7] = f2bs(b.w);
  return r;
}

// ---------------------------------------------------------------------------
// K0: meta (row_start, len per batch) + dtype sniffer + W1 -> bf16 convert.
// w1b is written in MFMA B-fragment order: fragment (ct,ks) holds
// B[n=ct*16+(lane&15)][k=ks*32+(lane>>4)*8+j] at w1b[((ct*6+ks)*64+lane)*8+j]
// so h_mfma's fragment loads are lane-contiguous 1KB (coalesced).
// ---------------------------------------------------------------------------
__global__ void meta_kernel(const void* __restrict__ xt,
                            const int* __restrict__ bidx, const int* __restrict__ pidx,
                            int N, int B, int* __restrict__ rs, int* __restrict__ ln,
                            int* __restrict__ flag,
                            const void* __restrict__ W1, bf16* __restrict__ w1b, int w1n) {
  int isbf_l = 0;
  {
    unsigned w = ((const unsigned*)xt)[threadIdx.x & 63];
    unsigned lo = w & 0xffffu;
    unsigned ex = (lo >> 7) & 0xffu;
    bool sane = ((lo & 0x7fffu) == 0u) || (ex >= 96u && ex <= 134u);
    unsigned long long m = __ballot(sane);
    isbf_l = (__popcll(m) >= 48) ? 1 : 0;
    if (blockIdx.x == 0 && threadIdx.x == 0) flag[0] = isbf_l;
  }
  int stride = gridDim.x * blockDim.x;
  int g0 = blockIdx.x * blockDim.x + threadIdx.x;
  for (int i = g0; i < N; i += stride) {
    int b = bidx[i];
    if ((unsigned)b >= (unsigned)B) continue;
    if (i == 0 || bidx[i - 1] != b) rs[b] = i;
    if (i == N - 1 || bidx[i + 1] != b) ln[b] = pidx[i] + 1;
  }
  for (int i = g0; i < w1n; i += stride) {
    int o = i / 192, k = i - o * 192;          // W1[o][k], o<128, k<192
    int ct = o >> 4, n = o & 15;
    int ks = k >> 5, rem = k & 31;
    int q = rem >> 3, j = rem & 7;
    int fi = ((ct * 6 + ks) * 64 + q * 16 + n) * 8 + j;
    w1b[fi] = __float2bfloat16(ld1(W1, i, isbf_l));
  }
}

// ---------------------------------------------------------------------------
// Kf: flag-aware zero fill of x_out (fallback when ws too small)
// ---------------------------------------------------------------------------
__global__ void zfill_kernel(void* out, const int* __restrict__ flag, long long n) {
  const int isbf = flag[0];
  long long i = (long long)blockIdx.x * blockDim.x + threadIdx.x;
  long long stride = (long long)gridDim.x * blockDim.x;
  for (; i < n; i += stride) st1(out, (size_t)i, isbf, 0.f);
}

// ---------------------------------------------------------------------------
// K1: h = leaky(bn1(concat(x_temp, x_stat[bidx]) @ W1^T + b1))  via MFMA.
// ---------------------------------------------------------------------------
__global__ __launch_bounds__(256) void h_mfma_kernel(
    const void* __restrict__ xt, const void* __restrict__ xsg,
    const int* __restrict__ bidx, const bf16* __restrict__ w1b,
    const void* __restrict__ b1,
    const void* __restrict__ g1, const void* __restrict__ be1,
    const void* __restrict__ mn1, const void* __restrict__ vr1,
    const int* __restrict__ flag, bf16* __restrict__ hout, int N) {
  const int isbf = flag[0];
  const int tid = threadIdx.x, lane = tid & 63, wv = tid >> 6;
  const int m16 = lane & 15, quad = lane >> 4;
  const int row0 = blockIdx.x * 64 + wv * 16;
  const int m = row0 + m16;
  const int mc = (m < N) ? m : (N - 1);
  const int bi = bidx[mc];

  short8 af[6];
  if (isbf) {
    const bf16* xr = (const bf16*)xt + (size_t)mc * 128 + quad * 8;
#pragma unroll
    for (int ks = 0; ks < 4; ++ks) af[ks] = *(const short8*)(xr + ks * 32);
    const bf16* sr = (const bf16*)xsg + (size_t)bi * 64 + quad * 8;
    af[4] = *(const short8*)sr;
    af[5] = *(const short8*)(sr + 32);
  } else {
    const float* xr = (const float*)xt + (size_t)mc * 128 + quad * 8;
#pragma unroll
    for (int ks = 0; ks < 4; ++ks) af[ks] = pack8f(xr + ks * 32);
    const float* sr = (const float*)xsg + (size_t)bi * 64 + quad * 8;
    af[4] = pack8f(sr);
    af[5] = pack8f(sr + 32);
  }

  f32x4 acc[8];
#pragma unroll
  for (int ct = 0; ct < 8; ++ct) acc[ct] = (f32x4){0.f, 0.f, 0.f, 0.f};

  const short8* wf = (const short8*)w1b;   // fragment-ordered (see meta)
#pragma unroll
  for (int ks = 0; ks < 6; ++ks) {
#pragma unroll
    for (int ct = 0; ct < 8; ++ct) {
      short8 bfrag = wf[(ct * 6 + ks) * 64 + lane];
      acc[ct] = __builtin_amdgcn_mfma_f32_16x16x32_bf16(af[ks], bfrag, acc[ct], 0, 0, 0);
    }
  }

#pragma unroll
  for (int ct = 0; ct < 8; ++ct) {
    const int o = ct * 16 + m16;
    float k1 = ld1(g1, o, isbf) * rsqrtf(ld1(vr1, o, isbf) + EPS);
    float k0 = ld1(be1, o, isbf) - ld1(mn1, o, isbf) * k1;
    float bias = ld1(b1, o, isbf);
#pragma unroll
    for (int r = 0; r < 4; ++r) {
      int mr = row0 + quad * 4 + r;
      if (mr < N) {
        float v = (acc[ct][r] + bias) * k1 + k0;
        v = (v >= 0.f) ? v : NSLOPE * v;
        hout[(size_t)mr * 128 + o] = __float2bfloat16(v);
      }
    }
  }
}

// ---------------------------------------------------------------------------
// K2: x_stat_out = leaky(bn2(x_stat @ W2^T + b2))
// ---------------------------------------------------------------------------
__global__ __launch_bounds__(64) void stat_kernel(
    const void* __restrict__ xstat, const void* __restrict__ W2,
    const void* __restrict__ b2, const void* __restrict__ g2,
    const void* __restrict__ be2, const void* __restrict__ mn2,
    const void* __restrict__ vr2, const int* __restrict__ flag,
    void* __restrict__ out, long long obase) {
  __shared__ float xs[64];
  const int isbf = flag[0];
  const int b = blockIdx.x, o = threadIdx.x;
  xs[o] = ld1(xstat, b * 64 + o, isbf);
  __syncthreads();
  float acc = ld1(b2, o, isbf);
#pragma unroll 8
  for (int j = 0; j < 64; ++j) acc += xs[j] * ld1(W2, o * 64 + j, isbf);
  float k1 = ld1(g2, o, isbf) * rsqrtf(ld1(vr2, o, isbf) + EPS);
  float k0 = ld1(be2, o, isbf) - ld1(mn2, o, isbf) * k1;
  float v = acc * k1 + k0;
  v = (v >= 0.f) ? v : NSLOPE * v;
  st1(out, (size_t)(obase + b * 64 + o), isbf, v);
}

// ---------------------------------------------------------------------------
// K3: fused online-softmax MFMA attention, wave-independent q-tiles.
// Block = 64 query rows (4 waves x 16 rows each), s-chunks of 64.
// Per chunk per wave: 16 QK + 16 PV + 16 taV MFMAs; softmax entirely
// in-register (shfl over m16) -- no cross-wave stats, ONE barrier/chunk.
// vT[buf][c][s] double-buffered, stride 72 shorts: rows 16B-aligned for
// direct short8 reads, <=2-way bank aliasing on both scatter-writes and
// b128 reads. Staging split (T14): global loads issued at iteration top,
// LDS writes after PV, barrier at iteration end.
// ---------------------------------------------------------------------------
__global__ __launch_bounds__(256, 2) void attn_mfma_kernel(
    const void* __restrict__ ta, const bf16* __restrict__ h,
    const int* __restrict__ rs_arr, const int* __restrict__ ln_arr,
    const int* __restrict__ flag, void* __restrict__ xout, int T, int N) {
  __shared__ __align__(16) unsigned short vT[2][128][72];  // 36864 B
  __shared__ __align__(16) unsigned short Pw[4][16][72];   //  9216 B

  const int b = blockIdx.y, t0 = blockIdx.x * 64;
  const int len = ln_arr[b];
  if (t0 >= len) return;               // uniform exit before any barrier
  const int isbf = flag[0];
  const int rs = rs_arr[b];
  const int tid = threadIdx.x;
  const int lane = tid & 63, wv = tid >> 6;
  const int m16 = lane & 15, quad = lane >> 4;
  const int t0w = t0 + wv * 16;        // this wave's 16 query rows

  // ---- Q fragments: A[m=t][k=c], m=lane&15, k=quad*8+j (+32*ks) ----
  short8 qf[4];
  {
    int qrow = rs + t0w + m16;
    if (qrow > N - 1) qrow = N - 1;    // clamp: rows t>=len never stored
    const bf16* qp = h + (size_t)qrow * 128 + quad * 8;
#pragma unroll
    for (int ks = 0; ks < 4; ++ks) qf[ks] = *(const short8*)(qp + ks * 32);
  }

  const float scale = 0.08838834764831845f;  // 1/sqrt(128)
  const short8 zero8 = {0, 0, 0, 0, 0, 0, 0, 0};
  const uint4 zz = {0, 0, 0, 0};
  const size_t tarow = ((size_t)b * T + (t0w + m16)) * (size_t)T;
  const int c8base = wv * 32;          // this wave stages channels c8base..+31

  f32x4 accp[8], acct[8];
#pragma unroll
  for (int ct = 0; ct < 8; ++ct) {
    accp[ct] = (f32x4){0.f, 0.f, 0.f, 0.f};
    acct[ct] = (f32x4){0.f, 0.f, 0.f, 0.f};
  }
  float mrun[4], lrun[4];
#pragma unroll
  for (int r = 0; r < 4; ++r) { mrun[r] = -INFINITY; lrun[r] = 0.f; }

  // ---- prologue: stage chunk 0 (lane = s, wave's 32-channel slice) ----
  {
    int srow = lane;                   // s0 = 0
    bool v = srow < len;
    const bf16* src = h + (size_t)(rs + (v ? srow : 0)) * 128;
#pragma unroll
    for (int it = 0; it < 4; ++it) {
      int c8 = c8base + it * 8;
      uint4 u = v ? *(const uint4*)(src + c8) : zz;
      const unsigned short* a = (const unsigned short*)&u;
#pragma unroll
      for (int j = 0; j < 8; ++j) vT[0][c8 + j][lane] = a[j];
    }
  }
  __syncthreads();

  const int nchunk = (len + 63) >> 6;
  for (int ci = 0; ci < nchunk; ++ci) {
    const int s0 = ci << 6;
    const int p = ci & 1;
    const bool have_next = (ci + 1 < nchunk);

    // ---- stage-load for next chunk: issue early, write after PV ----
    uint4 su0 = zz, su1 = zz, su2 = zz, su3 = zz;
    if (have_next) {
      int srow = s0 + 64 + lane;
      bool v = srow < len;
      const bf16* src = h + (size_t)(rs + (v ? srow : 0)) * 128;
      if (v) {
        su0 = *(const uint4*)(src + c8base);
        su1 = *(const uint4*)(src + c8base + 8);
        su2 = *(const uint4*)(src + c8base + 16);
        su3 = *(const uint4*)(src + c8base + 24);
      }
    }

    // ---- temp_attn A-frags for this wave's rows ----
    short8 taf0, taf1;
    if (isbf) {
      const bf16* tp = (const bf16*)ta + tarow + s0 + quad * 8;
      taf0 = *(const short8*)tp;
      taf1 = *(const short8*)(tp + 32);
    } else {
      const float* tp = (const float*)ta + tarow + s0 + quad * 8;
      taf0 = pack8f(tp);
      taf1 = pack8f(tp + 32);
    }

    // ---- QK: S[t=quad*4+r][s=st*16+m16]; K rows from global (L1-hot) ----
    f32x4 sa[4];
    bool sval[4];
#pragma unroll
    for (int st = 0; st < 4; ++st) {
      int srow = s0 + st * 16 + m16;
      bool v = srow < len;
      sval[st] = v;
      const bf16* kp = h + (size_t)(rs + (v ? srow : 0)) * 128 + quad * 8;
      f32x4 a0 = (f32x4){0.f, 0.f, 0.f, 0.f};
#pragma unroll
      for (int ks = 0; ks < 4; ++ks) {
        short8 kf = v ? *(const short8*)(kp + ks * 32) : zero8;
        a0 = __builtin_amdgcn_mfma_f32_16x16x32_bf16(qf[ks], kf, a0, 0, 0, 0);
      }
      sa[st] = a0;
    }

    // ---- in-wave online softmax ----
    float cm[4];
#pragma unroll
    for (int r = 0; r < 4; ++r) cm[r] = -INFINITY;
#pragma unroll
    for (int st = 0; st < 4; ++st) {
#pragma unroll
      for (int r = 0; r < 4; ++r)
        cm[r] = fmaxf(cm[r], sval[st] ? sa[st][r] * scale : -INFINITY);
    }
#pragma unroll
    for (int off = 1; off <= 8; off <<= 1) {
#pragma unroll
      for (int r = 0; r < 4; ++r) cm[r] = fmaxf(cm[r], __shfl_xor(cm[r], off, 64));
    }
    float al[4], csum[4];
#pragma unroll
    for (int r = 0; r < 4; ++r) {
      float mnew = fmaxf(mrun[r], cm[r]);   // finite: col s0 always valid
      al[r] = __expf(mrun[r] - mnew);       // 0 on first chunk
      mrun[r] = mnew;
      csum[r] = 0.f;
    }
#pragma unroll
    for (int st = 0; st < 4; ++st) {
#pragma unroll
      for (int r = 0; r < 4; ++r) {
        float pv = sval[st] ? __expf(sa[st][r] * scale - mrun[r]) : 0.f;
        csum[r] += pv;
        Pw[wv][quad * 4 + r][st * 16 + m16] = (unsigned short)f2bs(pv);
      }
    }
#pragma unroll
    for (int off = 1; off <= 8; off <<= 1) {
#pragma unroll
      for (int r = 0; r < 4; ++r) csum[r] += __shfl_xor(csum[r], off, 64);
    }
#pragma unroll
    for (int r = 0; r < 4; ++r) lrun[r] = lrun[r] * al[r] + csum[r];

    // rescale P-accumulator by alpha (ta-acc is linear, untouched)
#pragma unroll
    for (int ct = 0; ct < 8; ++ct) {
#pragma unroll
      for (int r = 0; r < 4; ++r) accp[ct][r] *= al[r];
    }

    // ---- PV + taV: B-frags direct short8 from vT[p] (same-wave Pw read) ----
#pragma unroll
    for (int ks = 0; ks < 2; ++ks) {
      short8 pf = *(const short8*)&Pw[wv][m16][ks * 32 + quad * 8];
      short8 tf = ks ? taf1 : taf0;
#pragma unroll
      for (int ct = 0; ct < 8; ++ct) {
        short8 bfv = *(const short8*)&vT[p][ct * 16 + m16][ks * 32 + quad * 8];
        accp[ct] = __builtin_amdgcn_mfma_f32_16x16x32_bf16(pf, bfv, accp[ct], 0, 0, 0);
        acct[ct] = __builtin_amdgcn_mfma_f32_16x16x32_bf16(tf, bfv, acct[ct], 0, 0, 0);
      }
    }

    // ---- stage-write next chunk into vT[p^1] ----
    if (have_next) {
      const unsigned short* a0 = (const unsigned short*)&su0;
      const unsigned short* a1 = (const unsigned short*)&su1;
      const unsigned short* a2 = (const unsigned short*)&su2;
      const unsigned short* a3 = (const unsigned short*)&su3;
#pragma unroll
      for (int j = 0; j < 8; ++j) {
        vT[p ^ 1][c8base + j][lane]      = a0[j];
        vT[p ^ 1][c8base + 8 + j][lane]  = a1[j];
        vT[p ^ 1][c8base + 16 + j][lane] = a2[j];
        vT[p ^ 1][c8base + 24 + j][lane] = a3[j];
      }
    }
    __syncthreads();   // vT[p] reads done everywhere; vT[p^1] writes visible
  }

  // ---- epilogue: analytic zero-pad term, normalize, add ta part ----
  const int nr = len - t0w;            // rows this wave owns (may be <=0)
#pragma unroll
  for (int r = 0; r < 4; ++r) {
    int t = quad * 4 + r;
    if (t < nr) {
      float m_r = mrun[r], l_r = lrun[r];
      float m_f = (len < T) ? fmaxf(m_r, 0.f) : m_r;
      float corr = __expf(m_r - m_f);
      float l_f = l_r * corr + (float)(T - len) * __expf(-m_f);
      float os = corr / l_f;
      size_t ob = (size_t)(rs + t0w + t) * 128;
#pragma unroll
      for (int ct = 0; ct < 8; ++ct)
        st1(xout, ob + ct * 16 + m16, isbf, accp[ct][r] * os + acct[ct][r]);
    }
  }
}

// ---------------------------------------------------------------------------
extern "C" void kernel_launch(void* const* d_in, const int* in_sizes, int n_in,
                              void* d_out, int out_size, void* d_ws, size_t ws_size,
                              hipStream_t stream) {
  const void* x_temp    = d_in[0];
  const void* x_stat    = d_in[1];
  const void* temp_attn = d_in[2];
  const int N = in_sizes[0] / 128;      // 23450
  const int B = in_sizes[1] / 64;       // 32
  long long tt = (long long)in_sizes[2] / B;
  int T = 1; while ((long long)(T + 1) * (T + 1) <= tt) ++T;  // isqrt -> 1024

  int p = 3;
  while (p < n_in && in_sizes[p] != N) ++p;
  const int* batch_idx = (const int*)d_in[p++];
  const int* pos_idx   = (const int*)d_in[p++];
  const void* W1 = d_in[p++];
  const void* b1 = d_in[p++];
  const void* g1 = d_in[p++];
  const void* be1= d_in[p++];
  const void* mn1= d_in[p++];
  const void* vr1= d_in[p++];
  const void* W2 = d_in[p++];
  const void* b2 = d_in[p++];
  const void* g2 = d_in[p++];
  const void* be2= d_in[p++];
  const void* mn2= d_in[p++];
  const void* vr2= d_in[p++];

  int*  meta = (int*)d_ws;
  int*  rs   = meta;
  int*  lnp  = meta + B;
  int*  flag = meta + 2 * B;
  bf16* h    = (bf16*)((char*)d_ws + 1024);
  bf16* w1b  = h + (size_t)N * 128;
  const int w1n = 128 * 192;
  size_t need = 1024 + (size_t)N * 128 * sizeof(bf16) + (size_t)w1n * sizeof(bf16);

  long long obase = (long long)N * 128;

  meta_kernel<<<90, 256, 0, stream>>>(x_temp, batch_idx, pos_idx, N, B, rs, lnp,
                                      flag, W1, w1b, w1n);
  stat_kernel<<<B, 64, 0, stream>>>(x_stat, W2, b2, g2, be2, mn2, vr2, flag,
                                    d_out, obase);
  if (ws_size >= need) {
    h_mfma_kernel<<<(N + 63) / 64, 256, 0, stream>>>(x_temp, x_stat, batch_idx,
                                                     w1b, b1, g1, be1, mn1, vr1,
                                                     flag, h, N);
    attn_mfma_kernel<<<dim3((T + 63) / 64, B), 256, 0, stream>>>(
        temp_attn, h, rs, lnp, flag, d_out, T, N);
  } else {
    zfill_kernel<<<512, 256, 0, stream>>>(d_out, flag, obase);
  }
}